// Round 8
// baseline (27.826 us; speedup 1.0000x reference)
//
#include <hip/hip_runtime.h>

#define PI_F 3.14159265358979323846f

constexpr int WPB = 4;   // waves per block (256 threads)

typedef float f4 __attribute__((ext_vector_type(4)));

__global__ __launch_bounds__(256) void ptok_persist(
    const int* __restrict__ char_idx,
    const int* __restrict__ positions,
    const float* __restrict__ W,
    f4* __restrict__ out,
    int S, int nrows, int nwaves)
{
    const int lane = threadIdx.x & 63;
    const int wid0 = __builtin_amdgcn_readfirstlane(
        blockIdx.x * WPB + (threadIdx.x >> 6));
    const float fj = (float)lane;
    const int lm1 = (lane + 63) & 63;

    // each wave: 2 consecutive rows per iteration, stride 2*nwaves
    for (int row = wid0 * 2; row < nrows; row += 2 * nwaves) {
        f4 o[2][2];
        #pragma unroll
        for (int r = 0; r < 2; ++r) {
            const int rr = row + r;
            const int s = rr & (S - 1);                // S = 8192 (pow2)
            const int c = char_idx[rr];                // uniform -> s_load
            const unsigned pv = (unsigned)positions[s];
            // sin(0.1*pi*p): exact integer period 20 -> small-angle __sinf
            const float pp = __sinf((float)(pv % 20u) * (0.1f * PI_F));

            const float* p = W + c * 8;
            const float omega = p[0] * 2.0f;
            const float A1 = p[1];
            const float A2p = 2.0f * p[2];             // folds sin2a = 2 s c
            const float A3 = p[3];
            const float bp = p[4] * pp;                // beta * pos_phase
            const float g = 1.0f / (1.0f + __expf(-p[5]));
            const float phi = p[6] * PI_F;

            float w[2];
            #pragma unroll
            for (int k = 0; k < 2; ++k) {
                const float j = fj + 64.0f * k;
                const float a = fmaf(omega, j, phi);
                const float sa = __sinf(a);
                const float ca = __cosf(a);
                const float env = __expf(-g * j);
                float acc = A1 * sa;
                acc = fmaf(A2p, sa * ca, acc);
                acc = fmaf(A3, sa * fmaf(-4.0f, sa * sa, 3.0f), acc);
                w[k] = fmaf(bp, j, acc * env);
            }

            // roll(wave,1): prev[j] = wave[(j-1) & 127]
            const float u0 = __shfl(w[0], lm1, 64);
            const float u1 = __shfl(w[1], lm1, 64);
            const float prev0 = (lane == 0) ? u1 : u0; // j=0  -> wave[127]
            const float prev1 = (lane == 0) ? u0 : u1; // j=64 -> wave[63]

            o[r][0].x = w[0]; o[r][0].y = prev0;
            o[r][0].z = __sinf(w[0]); o[r][0].w = __cosf(w[0]);
            o[r][1].x = w[1]; o[r][1].y = prev1;
            o[r][1].z = __sinf(w[1]); o[r][1].w = __cosf(w[1]);
        }

        // 4 independent 1 KB nontemporal stores, back-to-back
        f4* orow0 = out + ((size_t)row << 7);
        __builtin_nontemporal_store(o[0][0], orow0 + lane);
        __builtin_nontemporal_store(o[0][1], orow0 + 64 + lane);
        __builtin_nontemporal_store(o[1][0], orow0 + 128 + lane);
        __builtin_nontemporal_store(o[1][1], orow0 + 192 + lane);
    }
}

extern "C" void kernel_launch(void* const* d_in, const int* in_sizes, int n_in,
                              void* d_out, int out_size, void* d_ws, size_t ws_size,
                              hipStream_t stream) {
    const int* char_idx  = (const int*)d_in[0];   // [B*S]
    const int* positions = (const int*)d_in[1];   // [S]
    const float* W       = (const float*)d_in[2]; // [95, 8]

    const int nrows = in_sizes[0];                // B*S = 65536
    const int S = in_sizes[1];                    // 8192

    const int nblocks = 2048;                     // 8 blocks/CU, persistent
    const int nwaves = nblocks * WPB;             // 8192 waves
    ptok_persist<<<nblocks, 256, 0, stream>>>(
        char_idx, positions, W, (f4*)d_out, S, nrows, nwaves);
}